// Round 10
// baseline (283.724 us; speedup 1.0000x reference)
//
#include <hip/hip_runtime.h>
#include <stdint.h>

#define N_NODES 20000
#define N_EDGES 320000
#define K_MIX 5
#define IN_F 256
#define OUT_F 128
#define NT 11              /* 1 + 2K j-slices */

typedef __attribute__((ext_vector_type(8))) short short8;
typedef __attribute__((ext_vector_type(4))) float floatx4;

__device__ __forceinline__ float bf2f(unsigned int u) {
  union { unsigned int i; float f; } v;
  v.i = (u & 0xffffu) << 16;
  return v.f;
}
__device__ __forceinline__ unsigned short f2bf(float f) {
  union { float f; unsigned int i; } v;
  v.f = f;
  unsigned int x = v.i;
  unsigned int r = (x + 0x7fffu + ((x >> 16) & 1u)) >> 16;
  return (unsigned short)r;
}

// E[relu(X)], X ~ N(mu, sig) (sig is variance). Fast erf: A&S 7.1.26 reusing
// exp(-w^2/2) (== exp(-x^2) for x = w/sqrt2). |erf err| < 1.5e-7.
__device__ __forceinline__ float exrelu(float mu, float sig) {
  if (sig < 1e-30f) return fmaxf(mu, 0.f);
  float ss = sqrtf(sig);
  float w = mu / ss;
  float e = __expf(-0.5f * w * w);
  float axv = fabsf(w) * 0.70710678118654752f;
  float t = 1.f / (1.f + 0.3275911f * axv);
  float poly = t * (0.254829592f +
              t * (-0.284496736f +
              t * (1.421413741f +
              t * (-1.453152027f + t * 1.061405429f))));
  float erfv = 1.f - poly * e;
  erfv = copysignf(erfv, w);
  return ss * (e * 0.3989422804014327f + 0.5f * w * (1.f + erfv));
}

// ---------------- degree ----------------
__global__ void k_deg(const int* __restrict__ row, int* __restrict__ deg) {
  int t = blockIdx.x * 256 + threadIdx.x;
  if (t < N_EDGES) atomicAdd(&deg[row[t]], 1);
}

// ---------------- CSR build: scan (+dinv fused) + scatter ----------------
__global__ void k_scan1(const int* __restrict__ deg, int* __restrict__ startofs,
                        int* __restrict__ bsums, float* __restrict__ dinv) {
  __shared__ int sd[256];
  int t = threadIdx.x;
  int i = blockIdx.x * 256 + t;
  int v = (i < N_NODES) ? deg[i] : 0;
  if (i < N_NODES) dinv[i] = rsqrtf((float)(v + 1));  // +1 self-loop
  sd[t] = v;
  __syncthreads();
  for (int off = 1; off < 256; off <<= 1) {
    int u = (t >= off) ? sd[t - off] : 0;
    __syncthreads();
    sd[t] += u;
    __syncthreads();
  }
  if (i < N_NODES) startofs[i] = sd[t] - v;
  if (t == 255) bsums[blockIdx.x] = sd[255];
}

__global__ void k_scan2(int* __restrict__ bsums, int nb) {
  __shared__ int sd[128];
  int t = threadIdx.x;
  int v = (t < nb) ? bsums[t] : 0;
  sd[t] = v;
  __syncthreads();
  for (int off = 1; off < 128; off <<= 1) {
    int u = (t >= off) ? sd[t - off] : 0;
    __syncthreads();
    sd[t] += u;
    __syncthreads();
  }
  if (t < nb) bsums[t] = sd[t] - v;  // exclusive
}

__global__ void k_scan3(int* __restrict__ startofs, int* __restrict__ cursor,
                        const int* __restrict__ bsums) {
  int i = blockIdx.x * 256 + threadIdx.x;
  if (i < N_NODES) {
    int s0 = startofs[i] + bsums[blockIdx.x];
    startofs[i] = s0;
    cursor[i] = s0;
  }
}

__global__ void k_scatter(const int* __restrict__ row, const int* __restrict__ col,
                          const float* __restrict__ dinv, int* __restrict__ cursor,
                          int* __restrict__ csr_col, float* __restrict__ csr_w) {
  int t = blockIdx.x * 256 + threadIdx.x;
  if (t < N_EDGES) {
    int r = row[t], c = col[t];
    int p = atomicAdd(&cursor[r], 1);
    csr_col[p] = c;
    csr_w[p] = dinv[r] * dinv[c];
  }
}

// ---------------- B-matrix build: Bt[j][n][k] bf16 (transposed for MFMA B) ----
__global__ void k_buildB(const float* __restrict__ W, const float* __restrict__ means,
                         const float* __restrict__ logvars, unsigned short* __restrict__ Bt) {
  int idx = blockIdx.x * 256 + threadIdx.x;  // < 11*128*256
  int j = idx >> 15;
  int rem = idx & 32767;
  int n = rem >> 8;
  int kk = rem & 255;
  float wv = W[kk * OUT_F + n];
  float val;
  if (j == 0) val = wv;                                        // W
  else if (j <= 5) val = means[(j - 1) * IN_F + kk] * wv;      // means_k * W
  else val = expf(logvars[(j - 6) * IN_F + kk]) * wv * wv;     // var_k * W^2
  Bt[idx] = f2bf(val);
}

// ---- prep: pack x -> bf16 X0 (NaN marker 0x7FC0 for missing) + gamma ---------
__global__ void k_prepx(const float* __restrict__ x, const float* __restrict__ logp,
                        const float* __restrict__ means, const float* __restrict__ logvars,
                        unsigned short* __restrict__ X0, float* __restrict__ gamma) {
  __shared__ float s_mean[K_MIX * IN_F];
  __shared__ float s_rv[K_MIX * IN_F];
  int t = threadIdx.x;
  for (int j = t; j < K_MIX * IN_F; j += 256) {
    s_mean[j] = means[j];
    s_rv[j] = expf(-logvars[j]);  // 1/var
  }
  __syncthreads();
  int node = blockIdx.x * 4 + (t >> 6);
  if (node >= N_NODES) return;
  int lane = t & 63;
  float4 xv = *(const float4*)(x + (size_t)node * IN_F + 4 * lane);
  float xf[4] = {xv.x, xv.y, xv.z, xv.w};
  float gsum[K_MIX] = {0, 0, 0, 0, 0};
  ushort4 o;
  unsigned short* op = (unsigned short*)&o;
#pragma unroll
  for (int j = 0; j < 4; j++) {
    bool nn = (xf[j] != xf[j]);
    op[j] = nn ? (unsigned short)0x7FC0 : f2bf(xf[j]);
    if (!nn) {
      int fi = 4 * lane + j;
#pragma unroll
      for (int k = 0; k < K_MIX; k++) {
        float d = xf[j] - s_mean[k * IN_F + fi];
        gsum[k] += d * d * s_rv[k * IN_F + fi];
      }
    }
  }
  *(ushort4*)(X0 + node * IN_F + 4 * lane) = o;
#pragma unroll
  for (int k = 0; k < K_MIX; k++)
    for (int off = 32; off; off >>= 1) gsum[k] += __shfl_xor(gsum[k], off, 64);
  if (lane == 0) {
    float lg[K_MIX], mx = -1e30f;
#pragma unroll
    for (int k = 0; k < K_MIX; k++) {
      lg[k] = logp[k] - 0.5f * gsum[k];
      mx = fmaxf(mx, lg[k]);
    }
    float se = 0.f;
#pragma unroll
    for (int k = 0; k < K_MIX; k++) { lg[k] = expf(lg[k] - mx); se += lg[k]; }
    float inv = 1.f / se;
#pragma unroll
    for (int k = 0; k < K_MIX; k++) gamma[node * K_MIX + k] = lg[k] * inv;
  }
}

// ---- fused 3-way SpMM: A@x0 | A@m | A2@m  (ONE 64-thread BLOCK per node) -----
__global__ __launch_bounds__(64) void k_spmm(const unsigned short* __restrict__ X0,
                       const int* __restrict__ startofs, const int* __restrict__ deg,
                       const float* __restrict__ dinv, const int* __restrict__ csr_col,
                       const float* __restrict__ csr_w, unsigned short* __restrict__ G,
                       float* __restrict__ sArr) {
  int node = blockIdx.x;
  int lane = threadIdx.x;
  int fo = 4 * lane;
  float ax[4] = {0, 0, 0, 0}, am[4] = {0, 0, 0, 0}, am2[4] = {0, 0, 0, 0};
  float ssum = 0.f;
  float ws = dinv[node];
  ws = ws * ws;
  int st = startofs[node];
  int total = deg[node] + 1;  // virtual idx 0 = self loop, v>=1 -> edge v-1
  ushort4 zero4 = {0, 0, 0, 0};
  ushort4 B0 = zero4, B1 = zero4, B2 = zero4, B3 = zero4,
          B4 = zero4, B5 = zero4, B6 = zero4, B7 = zero4;
  float W0 = 0.f, W1 = 0.f, W2 = 0.f, W3 = 0.f,
        W4 = 0.f, W5 = 0.f, W6 = 0.f, W7 = 0.f;
  B0 = *(const ushort4*)(X0 + node * IN_F + fo); W0 = ws;
#define PFILL(S)                                                      \
  if (S < total) {                                                    \
    int c = csr_col[st + (S - 1)];                                    \
    W##S = csr_w[st + (S - 1)];                                       \
    B##S = *(const ushort4*)(X0 + c * IN_F + fo);                     \
  }
  PFILL(1) PFILL(2) PFILL(3) PFILL(4) PFILL(5) PFILL(6) PFILL(7)
#undef PFILL

#define STEP(S)                                                       \
  if (W##S != 0.f) {                                                  \
    float wv = W##S, wv2 = wv * wv;                                   \
    ssum += wv;                                                       \
    const unsigned short* xp = (const unsigned short*)&B##S;          \
    _Pragma("unroll")                                                 \
    for (int j = 0; j < 4; j++) {                                     \
      float xf = bf2f(xp[j]);                                         \
      bool nn = (xf != xf);                                           \
      ax[j] = fmaf(wv, nn ? 0.f : xf, ax[j]);                         \
      am[j] += nn ? wv : 0.f;                                         \
      am2[j] += nn ? wv2 : 0.f;                                       \
    }                                                                 \
  }                                                                   \
  if (base + 8 + S < total) {                                         \
    int c = csr_col[st + base + 7 + S];                               \
    W##S = csr_w[st + base + 7 + S];                                  \
    B##S = *(const ushort4*)(X0 + c * IN_F + fo);                     \
  } else {                                                            \
    W##S = 0.f;                                                       \
  }

  for (int base = 0; base < total; base += 8) {
    STEP(0) STEP(1) STEP(2) STEP(3) STEP(4) STEP(5) STEP(6) STEP(7)
  }
#undef STEP

  ushort4 o;
  o.x = f2bf(ax[0]); o.y = f2bf(ax[1]); o.z = f2bf(ax[2]); o.w = f2bf(ax[3]);
  *(ushort4*)(G + node * 768 + fo) = o;
  o.x = f2bf(am[0]); o.y = f2bf(am[1]); o.z = f2bf(am[2]); o.w = f2bf(am[3]);
  *(ushort4*)(G + node * 768 + 256 + fo) = o;
  o.x = f2bf(am2[0]); o.y = f2bf(am2[1]); o.z = f2bf(am2[2]); o.w = f2bf(am2[3]);
  *(ushort4*)(G + node * 768 + 512 + fo) = o;
  if (lane == 0) sArr[node] = ssum;
}

// ---- fused MFMA GEMM + epilogue: 128 rows x 16 cols, all 11 j-slices ---------
// A staged via LDS (BK=32, [s][q][r] chunks, r^(2q) swizzle: conflict-free).
// B frags direct from global (Bt = 720 KB, L2-resident). No T materialization.
__global__ __launch_bounds__(256) void k_gemmE(const unsigned short* __restrict__ G,
                                               const unsigned short* __restrict__ Bt,
                                               const float* __restrict__ gamma,
                                               const float* __restrict__ sArr,
                                               const float* __restrict__ bias,
                                               float* __restrict__ out) {
  __shared__ char Als[3 * 4 * 128 * 16];  // 24 KB: s*8192 + q*2048 + r*16
  __shared__ float lgam[128 * K_MIX];
  __shared__ float ls[128];
  int mt = blockIdx.x, ng = blockIdx.y;
  int row0 = mt * 128;
  int t = threadIdx.x, wave = t >> 6, lane = t & 63;
  int quad = lane >> 4, l16 = lane & 15;

  for (int i = t; i < 128 * K_MIX; i += 256) {
    int node = row0 + i / K_MIX;
    lgam[i] = (node < N_NODES) ? gamma[node * K_MIX + i % K_MIX] : 0.f;
  }
  if (t < 128) {
    int node = row0 + t;
    ls[t] = (node < N_NODES) ? sArr[node] : 0.f;
  }
  int colg = ng * 16 + l16;
  float bc = bias[colg];
  const unsigned short* Bcol = Bt + colg * 256 + quad * 8;

  floatx4 acc[2][NT];
  floatx4 z = {0.f, 0.f, 0.f, 0.f};
#pragma unroll
  for (int m = 0; m < 2; m++)
#pragma unroll
    for (int j = 0; j < NT; j++) acc[m][j] = z;

  int rbase = wave * 32;
  for (int k0 = 0; k0 < 256; k0 += 32) {
    __syncthreads();
    // stage A: 1536 16-B chunks (3 slices x 4 q x 128 r); 6 per thread.
    // f -> q = f&3, r = (f>>2)&127, s = f>>9; global: 4 lanes = 64 B contiguous.
#pragma unroll
    for (int i = 0; i < 6; i++) {
      int f = i * 256 + t;
      int q = f & 3;
      int r = (f >> 2) & 127;
      int s = f >> 9;
      int gr = row0 + r;
      if (gr >= N_NODES) gr = N_NODES - 1;
      *(uint4*)(Als + s * 8192 + q * 2048 + ((r ^ (q * 2)) & 127) * 16) =
          *(const uint4*)(G + gr * 768 + s * 256 + k0 + q * 8);
    }
    __syncthreads();
    // A fragments from LDS
    short8 af[3][2];
#pragma unroll
    for (int s = 0; s < 3; s++)
#pragma unroll
      for (int m = 0; m < 2; m++) {
        int r = rbase + m * 16 + l16;
        af[s][m] = *(const short8*)(Als + s * 8192 + quad * 2048 +
                                    ((r ^ (quad * 2)) & 127) * 16);
      }
    // j = 0 (cx), j = 1..5 (tm), j = 6..10 (tv); B direct from L2
#pragma unroll
    for (int j = 0; j < NT; j++) {
      int s = (j == 0) ? 0 : (j <= 5 ? 1 : 2);
      short8 b = *(const short8*)(Bcol + j * 32768 + k0);
      acc[0][j] = __builtin_amdgcn_mfma_f32_16x16x32_bf16(af[s][0], b, acc[0][j], 0, 0, 0);
      acc[1][j] = __builtin_amdgcn_mfma_f32_16x16x32_bf16(af[s][1], b, acc[1][j], 0, 0, 0);
    }
  }

  // epilogue in-register: out = sum_k gamma_k * exrelu(cx + tm_k + bias*s, tv_k)
#pragma unroll
  for (int m = 0; m < 2; m++) {
#pragma unroll
    for (int reg = 0; reg < 4; reg++) {
      int rl = rbase + m * 16 + quad * 4 + reg;
      int node = row0 + rl;
      float sv = ls[rl];
      float cx = acc[m][0][reg] + bc * sv;
      float a = 0.f;
#pragma unroll
      for (int k = 0; k < K_MIX; k++)
        a += lgam[rl * K_MIX + k] * exrelu(cx + acc[m][1 + k][reg], acc[m][6 + k][reg]);
      if (node < N_NODES) out[node * OUT_F + colg] = a;
    }
  }
}

extern "C" void kernel_launch(void* const* d_in, const int* in_sizes, int n_in,
                              void* d_out, int out_size, void* d_ws, size_t ws_size,
                              hipStream_t stream) {
  const float* x = (const float*)d_in[0];
  const int* ei = (const int*)d_in[1];
  const float* logp = (const float*)d_in[2];
  const float* means = (const float*)d_in[3];
  const float* lvar = (const float*)d_in[4];
  const float* W = (const float*)d_in[5];
  const float* bias = (const float*)d_in[6];
  float* out = (float*)d_out;
  const int* row = ei;
  const int* col = ei + N_EDGES;

  char* p = (char*)d_ws;
  auto alloc = [&](size_t bytes) -> char* {
    char* q = p;
    p += (bytes + 255) & ~((size_t)255);
    return q;
  };
  int* deg = (int*)alloc(N_NODES * 4);
  float* dinv = (float*)alloc(N_NODES * 4);
  int* startofs = (int*)alloc(N_NODES * 4);
  int* cursor = (int*)alloc(N_NODES * 4);
  int* bsums = (int*)alloc(128 * 4);
  int* csr_col = (int*)alloc((size_t)N_EDGES * 4);
  float* csr_w = (float*)alloc((size_t)N_EDGES * 4);
  float* gamma = (float*)alloc((size_t)N_NODES * K_MIX * 4);
  float* sArr = (float*)alloc(N_NODES * 4);
  unsigned short* Bt = (unsigned short*)alloc((size_t)NT * 128 * 256 * 2);
  unsigned short* X0 = (unsigned short*)alloc((size_t)N_NODES * IN_F * 2);
  unsigned short* G = (unsigned short*)alloc((size_t)N_NODES * 768 * 2);

  hipMemsetAsync(deg, 0, N_NODES * 4, stream);
  k_deg<<<(N_EDGES + 255) / 256, 256, 0, stream>>>(row, deg);
  k_scan1<<<79, 256, 0, stream>>>(deg, startofs, bsums, dinv);
  k_scan2<<<1, 128, 0, stream>>>(bsums, 79);
  k_scan3<<<79, 256, 0, stream>>>(startofs, cursor, bsums);
  k_scatter<<<(N_EDGES + 255) / 256, 256, 0, stream>>>(row, col, dinv, cursor, csr_col, csr_w);
  k_buildB<<<(NT * 128 * 256) / 256, 256, 0, stream>>>(W, means, lvar, Bt);
  k_prepx<<<N_NODES / 4, 256, 0, stream>>>(x, logp, means, lvar, X0, gamma);
  k_spmm<<<N_NODES, 64, 0, stream>>>(X0, startofs, deg, dinv, csr_col, csr_w, G, sArr);
  k_gemmE<<<dim3((N_NODES + 127) / 128, 8), 256, 0, stream>>>(G, Bt, gamma, sArr, bias, out);
}

// Round 11
// 239.530 us; speedup vs baseline: 1.1845x; 1.1845x over previous
//
#include <hip/hip_runtime.h>
#include <stdint.h>

#define N_NODES 20000
#define N_EDGES 320000
#define K_MIX 5
#define IN_F 256
#define OUT_F 128
#define NT 11              /* 1 + 2K j-slices */
#define TC (NT * OUT_F)    /* 1408 */
#define BT_ELEMS (NT * 128 * 256)

typedef __attribute__((ext_vector_type(8))) short short8;
typedef __attribute__((ext_vector_type(4))) float floatx4;

__device__ __forceinline__ float bf2f(unsigned int u) {
  union { unsigned int i; float f; } v;
  v.i = (u & 0xffffu) << 16;
  return v.f;
}
__device__ __forceinline__ float bf2f_hi(unsigned int u) {
  union { unsigned int i; float f; } v;
  v.i = u & 0xffff0000u;
  return v.f;
}
__device__ __forceinline__ unsigned short f2bf(float f) {
  union { float f; unsigned int i; } v;
  v.f = f;
  unsigned int x = v.i;
  unsigned int r = (x + 0x7fffu + ((x >> 16) & 1u)) >> 16;
  return (unsigned short)r;
}

// E[relu(X)], X ~ N(mu, sig) (sig is variance). Fast erf: A&S 7.1.26 reusing
// exp(-w^2/2) (== exp(-x^2) for x = w/sqrt2). |erf err| < 1.5e-7.
__device__ __forceinline__ float exrelu(float mu, float sig) {
  if (sig < 1e-30f) return fmaxf(mu, 0.f);
  float ss = sqrtf(sig);
  float w = mu / ss;
  float e = __expf(-0.5f * w * w);
  float axv = fabsf(w) * 0.70710678118654752f;
  float t = 1.f / (1.f + 0.3275911f * axv);
  float poly = t * (0.254829592f +
              t * (-0.284496736f +
              t * (1.421413741f +
              t * (-1.453152027f + t * 1.061405429f))));
  float erfv = 1.f - poly * e;
  erfv = copysignf(erfv, w);
  return ss * (e * 0.3989422804014327f + 0.5f * w * (1.f + erfv));
}

// ---------------- degree ----------------
__global__ void k_deg(const int* __restrict__ row, int* __restrict__ deg) {
  int t = blockIdx.x * 256 + threadIdx.x;
  if (t < N_EDGES) atomicAdd(&deg[row[t]], 1);
}

// ---------------- CSR build: scan (+dinv fused) + scatter ----------------
__global__ void k_scan1(const int* __restrict__ deg, int* __restrict__ startofs,
                        int* __restrict__ bsums, float* __restrict__ dinv) {
  __shared__ int sd[256];
  int t = threadIdx.x;
  int i = blockIdx.x * 256 + t;
  int v = (i < N_NODES) ? deg[i] : 0;
  if (i < N_NODES) dinv[i] = rsqrtf((float)(v + 1));  // +1 self-loop
  sd[t] = v;
  __syncthreads();
  for (int off = 1; off < 256; off <<= 1) {
    int u = (t >= off) ? sd[t - off] : 0;
    __syncthreads();
    sd[t] += u;
    __syncthreads();
  }
  if (i < N_NODES) startofs[i] = sd[t] - v;
  if (t == 255) bsums[blockIdx.x] = sd[255];
}

__global__ void k_scan2(int* __restrict__ bsums, int nb) {
  __shared__ int sd[128];
  int t = threadIdx.x;
  int v = (t < nb) ? bsums[t] : 0;
  sd[t] = v;
  __syncthreads();
  for (int off = 1; off < 128; off <<= 1) {
    int u = (t >= off) ? sd[t - off] : 0;
    __syncthreads();
    sd[t] += u;
    __syncthreads();
  }
  if (t < nb) bsums[t] = sd[t] - v;  // exclusive
}

__global__ void k_scan3(int* __restrict__ startofs, int* __restrict__ cursor,
                        const int* __restrict__ bsums) {
  int i = blockIdx.x * 256 + threadIdx.x;
  if (i < N_NODES) {
    int s0 = startofs[i] + bsums[blockIdx.x];
    startofs[i] = s0;
    cursor[i] = s0;
  }
}

__global__ void k_scatter(const int* __restrict__ row, const int* __restrict__ col,
                          const float* __restrict__ dinv, int* __restrict__ cursor,
                          int* __restrict__ csr_col, float* __restrict__ csr_w) {
  int t = blockIdx.x * 256 + threadIdx.x;
  if (t < N_EDGES) {
    int r = row[t], c = col[t];
    int p = atomicAdd(&cursor[r], 1);
    csr_col[p] = c;
    csr_w[p] = dinv[r] * dinv[c];
  }
}

// ---- B-matrix build: Bt[j][n][k] bf16 (+ rv = 1/var tail) --------------------
__global__ void k_buildB(const float* __restrict__ W, const float* __restrict__ means,
                         const float* __restrict__ logvars, unsigned short* __restrict__ Bt,
                         float* __restrict__ rv) {
  int idx = blockIdx.x * 256 + threadIdx.x;
  if (idx < BT_ELEMS) {
    int j = idx >> 15;
    int rem = idx & 32767;
    int n = rem >> 8;
    int kk = rem & 255;
    float wv = W[kk * OUT_F + n];
    float val;
    if (j == 0) val = wv;                                        // W
    else if (j <= 5) val = means[(j - 1) * IN_F + kk] * wv;      // means_k * W
    else val = expf(logvars[(j - 6) * IN_F + kk]) * wv * wv;     // var_k * W^2
    Bt[idx] = f2bf(val);
  } else {
    int r = idx - BT_ELEMS;
    if (r < K_MIX * IN_F) rv[r] = expf(-logvars[r]);             // 1/var
  }
}

// ---- prep: pack x -> XP rows [x0(4 bf16) | m(4 bf16)] per 16-B lane chunk ----
// Also gamma (GMM responsibilities). No LDS, no expf (rv precomputed).
__global__ void k_prepx(const float* __restrict__ x, const float* __restrict__ logp,
                        const float* __restrict__ means, const float* __restrict__ rv,
                        unsigned int* __restrict__ XP, float* __restrict__ gamma) {
  int t = threadIdx.x;
  int node = blockIdx.x * 4 + (t >> 6);
  if (node >= N_NODES) return;
  int lane = t & 63;
  int fi = 4 * lane;
  float4 xv = *(const float4*)(x + (size_t)node * IN_F + fi);
  float xf[4] = {xv.x, xv.y, xv.z, xv.w};
  float gsum[K_MIX] = {0, 0, 0, 0, 0};
  unsigned short x0p[4], mp[4];
#pragma unroll
  for (int j = 0; j < 4; j++) {
    bool nn = (xf[j] != xf[j]);
    x0p[j] = nn ? (unsigned short)0 : f2bf(xf[j]);
    mp[j] = nn ? (unsigned short)0x3F80 : (unsigned short)0;  // bf16 1.0 / 0.0
  }
#pragma unroll
  for (int k = 0; k < K_MIX; k++) {
    float4 mk = *(const float4*)(means + k * IN_F + fi);
    float4 rk = *(const float4*)(rv + k * IN_F + fi);
    float mka[4] = {mk.x, mk.y, mk.z, mk.w};
    float rka[4] = {rk.x, rk.y, rk.z, rk.w};
#pragma unroll
    for (int j = 0; j < 4; j++) {
      if (xf[j] == xf[j]) {
        float d = xf[j] - mka[j];
        gsum[k] += d * d * rka[j];
      }
    }
  }
  uint4 o;
  o.x = (unsigned int)x0p[0] | ((unsigned int)x0p[1] << 16);
  o.y = (unsigned int)x0p[2] | ((unsigned int)x0p[3] << 16);
  o.z = (unsigned int)mp[0] | ((unsigned int)mp[1] << 16);
  o.w = (unsigned int)mp[2] | ((unsigned int)mp[3] << 16);
  *(uint4*)(XP + node * 256 + 4 * lane) = o;
#pragma unroll
  for (int k = 0; k < K_MIX; k++)
    for (int off = 32; off; off >>= 1) gsum[k] += __shfl_xor(gsum[k], off, 64);
  if (lane == 0) {
    float lg[K_MIX], mx = -1e30f;
#pragma unroll
    for (int k = 0; k < K_MIX; k++) {
      lg[k] = logp[k] - 0.5f * gsum[k];
      mx = fmaxf(mx, lg[k]);
    }
    float se = 0.f;
#pragma unroll
    for (int k = 0; k < K_MIX; k++) { lg[k] = __expf(lg[k] - mx); se += lg[k]; }
    float inv = 1.f / se;
#pragma unroll
    for (int k = 0; k < K_MIX; k++) gamma[node * K_MIX + k] = lg[k] * inv;
  }
}

// ---- fused 3-way SpMM: A@x0 | A@m | A2@m  (ONE 64-thread BLOCK per node) -----
// One dwordx4 gather per edge/lane: [x0 x4 | m x4]. 12 FMA inner. Depth-8 pipe.
__global__ __launch_bounds__(64) void k_spmm(const unsigned int* __restrict__ XP,
                       const int* __restrict__ startofs, const int* __restrict__ deg,
                       const float* __restrict__ dinv, const int* __restrict__ csr_col,
                       const float* __restrict__ csr_w, unsigned short* __restrict__ G,
                       float* __restrict__ sArr) {
  int node = blockIdx.x;
  int lane = threadIdx.x;
  int fo = 4 * lane;
  float ax[4] = {0, 0, 0, 0}, am[4] = {0, 0, 0, 0}, am2[4] = {0, 0, 0, 0};
  float ssum = 0.f;
  float ws = dinv[node];
  ws = ws * ws;
  int st = startofs[node];
  int total = deg[node] + 1;  // virtual idx 0 = self loop, v>=1 -> edge v-1
  uint4 zero4 = {0, 0, 0, 0};
  uint4 B0 = zero4, B1 = zero4, B2 = zero4, B3 = zero4,
        B4 = zero4, B5 = zero4, B6 = zero4, B7 = zero4;
  float W0 = 0.f, W1 = 0.f, W2 = 0.f, W3 = 0.f,
        W4 = 0.f, W5 = 0.f, W6 = 0.f, W7 = 0.f;
  B0 = *(const uint4*)(XP + node * 256 + fo); W0 = ws;
#define PFILL(S)                                                      \
  if (S < total) {                                                    \
    int c = csr_col[st + (S - 1)];                                    \
    W##S = csr_w[st + (S - 1)];                                       \
    B##S = *(const uint4*)(XP + c * 256 + fo);                        \
  }
  PFILL(1) PFILL(2) PFILL(3) PFILL(4) PFILL(5) PFILL(6) PFILL(7)
#undef PFILL

#define STEP(S)                                                       \
  if (W##S != 0.f) {                                                  \
    float wv = W##S, wv2 = wv * wv;                                   \
    ssum += wv;                                                       \
    ax[0] = fmaf(wv, bf2f(B##S.x), ax[0]);                            \
    ax[1] = fmaf(wv, bf2f_hi(B##S.x), ax[1]);                         \
    ax[2] = fmaf(wv, bf2f(B##S.y), ax[2]);                            \
    ax[3] = fmaf(wv, bf2f_hi(B##S.y), ax[3]);                         \
    float m0 = bf2f(B##S.z), m1 = bf2f_hi(B##S.z);                    \
    float m2 = bf2f(B##S.w), m3 = bf2f_hi(B##S.w);                    \
    am[0] = fmaf(wv, m0, am[0]);                                      \
    am[1] = fmaf(wv, m1, am[1]);                                      \
    am[2] = fmaf(wv, m2, am[2]);                                      \
    am[3] = fmaf(wv, m3, am[3]);                                      \
    am2[0] = fmaf(wv2, m0, am2[0]);                                   \
    am2[1] = fmaf(wv2, m1, am2[1]);                                   \
    am2[2] = fmaf(wv2, m2, am2[2]);                                   \
    am2[3] = fmaf(wv2, m3, am2[3]);                                   \
  }                                                                   \
  if (base + 8 + S < total) {                                         \
    int c = csr_col[st + base + 7 + S];                               \
    W##S = csr_w[st + base + 7 + S];                                  \
    B##S = *(const uint4*)(XP + c * 256 + fo);                        \
  } else {                                                            \
    W##S = 0.f;                                                       \
  }

  for (int base = 0; base < total; base += 8) {
    STEP(0) STEP(1) STEP(2) STEP(3) STEP(4) STEP(5) STEP(6) STEP(7)
  }
#undef STEP

  ushort4 o;
  o.x = f2bf(ax[0]); o.y = f2bf(ax[1]); o.z = f2bf(ax[2]); o.w = f2bf(ax[3]);
  *(ushort4*)(G + node * 768 + fo) = o;
  o.x = f2bf(am[0]); o.y = f2bf(am[1]); o.z = f2bf(am[2]); o.w = f2bf(am[3]);
  *(ushort4*)(G + node * 768 + 256 + fo) = o;
  o.x = f2bf(am2[0]); o.y = f2bf(am2[1]); o.z = f2bf(am2[2]); o.w = f2bf(am2[3]);
  *(ushort4*)(G + node * 768 + 512 + fo) = o;
  if (lane == 0) sArr[node] = ssum;
}

// ---- MFMA GEMM, LDS-staged, XCD-swizzled: T = (G slice) @ B_jt, bf16 out -----
// Block id -> (xcd = id&7, seq = id>>3, jt = seq%11, mt = xcd + 8*(seq/11)):
// all 11 jt of one mt land on one XCD, consecutively -> A slices L2-resident.
__global__ __launch_bounds__(256) void k_gemm(const unsigned short* __restrict__ G,
                                              const unsigned short* __restrict__ Bt,
                                              unsigned short* __restrict__ T) {
  __shared__ char Als[128 * 64 * 2];  // 16 KB
  __shared__ char Bls[128 * 64 * 2];  // 16 KB
  int id = blockIdx.x;
  int xcd = id & 7;
  int s2 = id >> 3;
  int jt = s2 % 11;
  int mt = xcd + 8 * (s2 / 11);
  if (mt * 128 >= N_NODES) return;
  int aoff = (jt == 0) ? 0 : (jt <= 5 ? 256 : 512);
  int t = threadIdx.x, wave = t >> 6, lane = t & 63;
  int wr = wave >> 1, wc = wave & 1;
  int quad = lane >> 4, l16 = lane & 15;
  const unsigned short* Bp = Bt + (size_t)jt * 32768;

  floatx4 acc[4][4];
  floatx4 z = {0.f, 0.f, 0.f, 0.f};
#pragma unroll
  for (int mi = 0; mi < 4; mi++)
#pragma unroll
    for (int ni = 0; ni < 4; ni++) acc[mi][ni] = z;

  for (int k0 = 0; k0 < 256; k0 += 64) {
    __syncthreads();
#pragma unroll
    for (int i = 0; i < 4; i++) {
      int f = i * 256 + t;
      int r = f >> 3, cchunk = f & 7;
      int sw = cchunk ^ (r & 7);
      int gr = mt * 128 + r;
      if (gr >= N_NODES) gr = N_NODES - 1;
      *(uint4*)(Als + r * 128 + sw * 16) =
          *(const uint4*)(G + (size_t)gr * 768 + aoff + k0 + cchunk * 8);
      *(uint4*)(Bls + r * 128 + sw * 16) =
          *(const uint4*)(Bp + (size_t)r * 256 + k0 + cchunk * 8);
    }
    __syncthreads();
#pragma unroll
    for (int ks = 0; ks < 2; ks++) {
      int cc = ks * 4 + quad;
      short8 a[4], b[4];
#pragma unroll
      for (int mi = 0; mi < 4; mi++) {
        int r = wr * 64 + mi * 16 + l16;
        a[mi] = *(const short8*)(Als + r * 128 + (cc ^ (r & 7)) * 16);
      }
#pragma unroll
      for (int ni = 0; ni < 4; ni++) {
        int r = wc * 64 + ni * 16 + l16;
        b[ni] = *(const short8*)(Bls + r * 128 + (cc ^ (r & 7)) * 16);
      }
#pragma unroll
      for (int mi = 0; mi < 4; mi++)
#pragma unroll
        for (int ni = 0; ni < 4; ni++)
          acc[mi][ni] = __builtin_amdgcn_mfma_f32_16x16x32_bf16(a[mi], b[ni], acc[mi][ni], 0, 0, 0);
    }
  }
#pragma unroll
  for (int mi = 0; mi < 4; mi++)
#pragma unroll
    for (int ni = 0; ni < 4; ni++) {
      int gc = jt * 128 + wc * 64 + ni * 16 + l16;
#pragma unroll
      for (int reg = 0; reg < 4; reg++) {
        int gr = mt * 128 + wr * 64 + mi * 16 + quad * 4 + reg;
        if (gr < N_NODES) T[(size_t)gr * TC + gc] = f2bf(acc[mi][ni][reg]);
      }
    }
}

// ---------------- epilogue: Ex_relu + gamma-weighted combine ----------------
__global__ void k_final(const unsigned short* __restrict__ T, const float* __restrict__ gamma,
                        const float* __restrict__ sArr, const float* __restrict__ bias,
                        float* __restrict__ out) {
  int t = threadIdx.x;
  int node = blockIdx.x * 4 + (t >> 6);
  if (node >= N_NODES) return;
  int lane = t & 63;
  int o0 = 2 * lane;
  float g[K_MIX];
#pragma unroll
  for (int k = 0; k < K_MIX; k++) g[k] = gamma[node * K_MIX + k];
  float sv = sArr[node];
  float b0 = bias[o0], b1 = bias[o0 + 1];
  const unsigned short* Tr = T + (size_t)node * TC;
  unsigned int c0u = *(const unsigned int*)(Tr + o0);
  float cx0 = bf2f(c0u), cx1 = bf2f_hi(c0u);
  float a0 = 0.f, a1 = 0.f;
#pragma unroll
  for (int k = 0; k < K_MIX; k++) {
    unsigned int tm = *(const unsigned int*)(Tr + 128 * (1 + k) + o0);
    unsigned int tv = *(const unsigned int*)(Tr + 128 * (6 + k) + o0);
    float mu0 = cx0 + bf2f(tm) + b0 * sv;
    float mu1 = cx1 + bf2f_hi(tm) + b1 * sv;
    a0 += g[k] * exrelu(mu0, bf2f(tv));
    a1 += g[k] * exrelu(mu1, bf2f_hi(tv));
  }
  float2 ov = {a0, a1};
  *(float2*)(out + (size_t)node * OUT_F + o0) = ov;
}

extern "C" void kernel_launch(void* const* d_in, const int* in_sizes, int n_in,
                              void* d_out, int out_size, void* d_ws, size_t ws_size,
                              hipStream_t stream) {
  const float* x = (const float*)d_in[0];
  const int* ei = (const int*)d_in[1];
  const float* logp = (const float*)d_in[2];
  const float* means = (const float*)d_in[3];
  const float* lvar = (const float*)d_in[4];
  const float* W = (const float*)d_in[5];
  const float* bias = (const float*)d_in[6];
  float* out = (float*)d_out;
  const int* row = ei;
  const int* col = ei + N_EDGES;

  char* p = (char*)d_ws;
  auto alloc = [&](size_t bytes) -> char* {
    char* q = p;
    p += (bytes + 255) & ~((size_t)255);
    return q;
  };
  int* deg = (int*)alloc(N_NODES * 4);
  float* dinv = (float*)alloc(N_NODES * 4);
  int* startofs = (int*)alloc(N_NODES * 4);
  int* cursor = (int*)alloc(N_NODES * 4);
  int* bsums = (int*)alloc(128 * 4);
  int* csr_col = (int*)alloc((size_t)N_EDGES * 4);
  float* csr_w = (float*)alloc((size_t)N_EDGES * 4);
  float* gamma = (float*)alloc((size_t)N_NODES * K_MIX * 4);
  float* sArr = (float*)alloc(N_NODES * 4);
  float* rv = (float*)alloc(K_MIX * IN_F * 4);
  unsigned short* Bt = (unsigned short*)alloc((size_t)BT_ELEMS * 2);
  unsigned int* XP = (unsigned int*)alloc((size_t)N_NODES * 256 * 4);
  unsigned short* G = (unsigned short*)alloc((size_t)N_NODES * 768 * 2);
  unsigned short* T = (unsigned short*)alloc((size_t)N_NODES * TC * 2);

  hipMemsetAsync(deg, 0, N_NODES * 4, stream);
  k_deg<<<(N_EDGES + 255) / 256, 256, 0, stream>>>(row, deg);
  k_scan1<<<79, 256, 0, stream>>>(deg, startofs, bsums, dinv);
  k_scan2<<<1, 128, 0, stream>>>(bsums, 79);
  k_scan3<<<79, 256, 0, stream>>>(startofs, cursor, bsums);
  k_scatter<<<(N_EDGES + 255) / 256, 256, 0, stream>>>(row, col, dinv, cursor, csr_col, csr_w);
  k_buildB<<<(BT_ELEMS + K_MIX * IN_F + 255) / 256, 256, 0, stream>>>(W, means, lvar, Bt, rv);
  k_prepx<<<N_NODES / 4, 256, 0, stream>>>(x, logp, means, rv, XP, gamma);
  k_spmm<<<N_NODES, 64, 0, stream>>>(XP, startofs, deg, dinv, csr_col, csr_w, G, sArr);
  k_gemm<<<8 * 20 * 11, 256, 0, stream>>>(G, Bt, T);
  k_final<<<N_NODES / 4, 256, 0, stream>>>(T, gamma, sArr, bias, out);
}